// Round 1
// baseline (269.469 us; speedup 1.0000x reference)
//
#include <hip/hip_runtime.h>

#define B_  4
#define N_  512
#define M_  512
#define D_  128
#define H_  128
#define EPS 1e-5f

typedef __attribute__((ext_vector_type(8))) short short8;
typedef __attribute__((ext_vector_type(4))) float f32x4;

__device__ __forceinline__ unsigned short f2bf(float f){
  unsigned u = __float_as_uint(f);
  u += 0x7fffu + ((u >> 16) & 1u);          // round-to-nearest-even
  return (unsigned short)(u >> 16);
}
__device__ __forceinline__ float bf2f(unsigned short s){
  return __uint_as_float(((unsigned)s) << 16);
}

// ---------------- prep 1: cx[b,n,h] = x@W1x + b1 ; cy[b,m,h] = y@W1y ----------------
__global__ __launch_bounds__(128) void prep_cxcy(
    const float* __restrict__ x, const float* __restrict__ y,
    const float* __restrict__ W1, const float* __restrict__ b1,
    float* __restrict__ cx, float* __restrict__ cy)
{
  const int row = blockIdx.x;            // 0..4095 ; first 2048 = x rows, rest = y rows
  const int h = threadIdx.x;             // 0..127
  const bool isX = row < B_ * N_;
  const int r = isX ? row : row - B_ * N_;
  const float* src = (isX ? x : y) + (size_t)r * D_;
  const float* W = W1 + (isX ? 0 : D_ * H_);
  float acc = isX ? b1[h] : 0.f;
#pragma unroll 8
  for (int d = 0; d < D_; ++d)
    acc = fmaf(src[d], W[d * H_ + h], acc);
  (isX ? cx : cy)[(size_t)r * H_ + h] = acc;
}

// ---------------- prep 2: W1d -> hi/lo bf16 fragments, MFMA B-layout ----------------
// layout: frag[kstep(4)][htile(8)][lane(64)][i(8)], k = ks*32 + 8*(lane>>4)+i, h = ht*16 + (lane&15)
__global__ __launch_bounds__(256) void prep_bfrag(
    const float* __restrict__ W1, unsigned short* __restrict__ bhi, unsigned short* __restrict__ blo)
{
  const int t = blockIdx.x * 256 + threadIdx.x;   // 0..16383
  const int i    = t & 7;
  const int lane = (t >> 3) & 63;
  const int ht   = (t >> 9) & 7;
  const int ks   = t >> 12;
  const int k = ks * 32 + ((lane >> 4) << 3) + i;
  const int h = ht * 16 + (lane & 15);
  const float v = W1[(size_t)(2 * D_ + k) * H_ + h];
  const unsigned short hi = f2bf(v);
  bhi[t] = hi;
  blo[t] = f2bf(v - bf2f(hi));
}

// ---------------- main fused kernel ----------------
// grid: (mblock=4, n=512, b=4), 256 threads = 4 waves.
// block computes C-tile: 128 m x 128 h; wave owns 32 m (2 MFMA row-tiles) x 128 h (8 col-tiles).
__global__ __launch_bounds__(256) void fused_main(
    const float* __restrict__ x, const float* __restrict__ y,
    const float* __restrict__ gamma, const float* __restrict__ beta,
    const float* __restrict__ W2, const float* __restrict__ b2,
    const float* __restrict__ cx, const float* __restrict__ cy,
    const unsigned short* __restrict__ bhi, float* __restrict__ out)
{
  __shared__ char smem[65536];           // [hi 32KB][lo 32KB] in fragment order

  const int tid = threadIdx.x;
  const int mblock = blockIdx.x, n = blockIdx.y, b = blockIdx.z;

  // stage 64KB of pre-permuted W1d hi/lo (bhi and blo are contiguous in ws)
  {
    const f32x4* src = (const f32x4*)bhi;
    f32x4* dst = (f32x4*)smem;
#pragma unroll
    for (int i = 0; i < 16; ++i)
      dst[i * 256 + tid] = src[i * 256 + tid];
  }
  __syncthreads();

  const int wave = tid >> 6, lane = tid & 63, g = lane >> 4, c = lane & 15;
  const int m0 = mblock * 128 + wave * 32;
  const float* xrow = x + (size_t)(b * N_ + n) * D_;

  f32x4 acc[2][8];
#pragma unroll
  for (int mt = 0; mt < 2; ++mt)
#pragma unroll
    for (int ht = 0; ht < 8; ++ht)
      acc[mt][ht] = (f32x4){0.f, 0.f, 0.f, 0.f};

#pragma unroll
  for (int ks = 0; ks < 4; ++ks) {
    const int d0 = ks * 32 + g * 8;
    f32x4 xa[2];
    xa[0] = *(const f32x4*)(xrow + d0);
    xa[1] = *(const f32x4*)(xrow + d0 + 4);

    short8 ahi[2], alo[2];
#pragma unroll
    for (int mt = 0; mt < 2; ++mt) {
      const int m = m0 + mt * 16 + c;     // A-operand rows indexed by lane&15
      const float* yrow = y + (size_t)(b * M_ + m) * D_ + d0;
      f32x4 ya[2];
      ya[0] = *(const f32x4*)(yrow);
      ya[1] = *(const f32x4*)(yrow + 4);
#pragma unroll
      for (int i = 0; i < 8; ++i) {
        const float dff = fabsf(xa[i >> 2][i & 3] - ya[i >> 2][i & 3]);
        const unsigned short hb = f2bf(dff);
        ahi[mt][i] = (short)hb;
        alo[mt][i] = (short)f2bf(dff - bf2f(hb));
      }
    }

    const char* basehi = smem + ((size_t)(ks * 8) * 64 + lane) * 16;
#pragma unroll
    for (int ht = 0; ht < 8; ++ht) {
      const short8 bh = *(const short8*)(basehi + ht * 1024);
      const short8 bl = *(const short8*)(basehi + 32768 + ht * 1024);
#pragma unroll
      for (int mt = 0; mt < 2; ++mt) {
        acc[mt][ht] = __builtin_amdgcn_mfma_f32_16x16x32_bf16(ahi[mt], bh, acc[mt][ht], 0, 0, 0);
        acc[mt][ht] = __builtin_amdgcn_mfma_f32_16x16x32_bf16(alo[mt], bh, acc[mt][ht], 0, 0, 0);
        acc[mt][ht] = __builtin_amdgcn_mfma_f32_16x16x32_bf16(ahi[mt], bl, acc[mt][ht], 0, 0, 0);
      }
    }
  }

  // ---------------- epilogue: + cx + cy, LayerNorm(H), ReLU, dot W2, +b2, ReLU ----------------
  const float* cxn = cx + (size_t)(b * N_ + n) * H_;
  float cxv[8], gv[8], bev[8], w2v[8];
#pragma unroll
  for (int ht = 0; ht < 8; ++ht) {
    const int h = ht * 16 + c;
    cxv[ht] = cxn[h]; gv[ht] = gamma[h]; bev[ht] = beta[h]; w2v[ht] = W2[h];
  }
  const float b2v = b2[0];

#pragma unroll
  for (int mt = 0; mt < 2; ++mt) {
#pragma unroll
    for (int r = 0; r < 4; ++r) {
      const int m = m0 + mt * 16 + g * 4 + r;      // C/D rows: (lane>>4)*4 + reg
      const float* cyrow = cy + (size_t)(b * M_ + m) * H_;
      float hv[8];
      float s1 = 0.f, s2 = 0.f;
#pragma unroll
      for (int ht = 0; ht < 8; ++ht) {
        const float v = acc[mt][ht][r] + cxv[ht] + cyrow[ht * 16 + c];
        hv[ht] = v; s1 += v; s2 += v * v;
      }
#pragma unroll
      for (int msk = 1; msk < 16; msk <<= 1) {
        s1 += __shfl_xor(s1, msk);
        s2 += __shfl_xor(s2, msk);
      }
      const float mu = s1 * (1.f / 128.f);
      const float var = s2 * (1.f / 128.f) - mu * mu;
      const float rs = rsqrtf(var + EPS);
      float o = 0.f;
#pragma unroll
      for (int ht = 0; ht < 8; ++ht) {
        const float hn = (hv[ht] - mu) * rs * gv[ht] + bev[ht];
        o += fmaxf(hn, 0.f) * w2v[ht];
      }
#pragma unroll
      for (int msk = 1; msk < 16; msk <<= 1)
        o += __shfl_xor(o, msk);
      if (c == 0)
        out[(size_t)(b * N_ + n) * M_ + m] = fmaxf(o + b2v, 0.f);
    }
  }
}

extern "C" void kernel_launch(void* const* d_in, const int* in_sizes, int n_in,
                              void* d_out, int out_size, void* d_ws, size_t ws_size,
                              hipStream_t stream) {
  const float* x     = (const float*)d_in[0];
  const float* y     = (const float*)d_in[1];
  const float* W1    = (const float*)d_in[2];
  const float* b1    = (const float*)d_in[3];
  const float* gamma = (const float*)d_in[4];
  const float* beta  = (const float*)d_in[5];
  const float* W2    = (const float*)d_in[6];
  const float* b2    = (const float*)d_in[7];
  float* out = (float*)d_out;

  char* ws = (char*)d_ws;
  float* cx = (float*)ws;                               // 4*512*128 f32 = 1MB
  float* cy = (float*)(ws + (1 << 20));                 // 1MB
  unsigned short* bhi = (unsigned short*)(ws + (2 << 20)); // 32KB
  unsigned short* blo = bhi + 16384;                    // contiguous 32KB (staged as one 64KB block)

  prep_cxcy<<<dim3(2 * B_ * N_), dim3(128), 0, stream>>>(x, y, W1, b1, cx, cy);
  prep_bfrag<<<dim3(64), dim3(256), 0, stream>>>(W1, bhi, blo);
  fused_main<<<dim3(M_ / 128, N_, B_), dim3(256), 0, stream>>>(
      x, y, gamma, beta, W2, b2, cx, cy, bhi, out);
}

// Round 3
// 212.487 us; speedup vs baseline: 1.2682x; 1.2682x over previous
//
#include <hip/hip_runtime.h>

#define B_  4
#define N_  512
#define M_  512
#define D_  128
#define H_  128
#define EPS 1e-5f

typedef __attribute__((ext_vector_type(8))) short short8;
typedef __attribute__((ext_vector_type(4))) float f32x4;
typedef __attribute__((ext_vector_type(4))) unsigned u32x4;

__device__ __forceinline__ unsigned short f2bf(float f){
  unsigned u = __float_as_uint(f);
  u += 0x7fffu + ((u >> 16) & 1u);          // round-to-nearest-even
  return (unsigned short)(u >> 16);
}
__device__ __forceinline__ float bf2f(unsigned short s){
  return __uint_as_float(((unsigned)s) << 16);
}

// hi/lo bf16 split of |d0|,|d1| packed into dwords.
// hi: round-half-up (a+0x8000, <=0.5ulp like RNE); lo = |d| - hi exactly
// compensates the hi rounding, then RNE to bf16 via v_cvt_pk_bf16_f32.
__device__ __forceinline__ void split2(float d0, float d1, unsigned &hp, unsigned &lp){
  unsigned a0 = __float_as_uint(d0) & 0x7fffffffu;   // |d|
  unsigned a1 = __float_as_uint(d1) & 0x7fffffffu;
  unsigned r0 = a0 + 0x8000u;                        // round half up to bf16
  unsigned r1 = a1 + 0x8000u;
  hp = __builtin_amdgcn_perm(r1, r0, 0x07060302u);   // pack top16(r0)|top16(r1)
  float lo0 = __uint_as_float(a0) - __uint_as_float(r0 & 0xffff0000u);
  float lo1 = __uint_as_float(a1) - __uint_as_float(r1 & 0xffff0000u);
  unsigned t;
  asm("v_cvt_pk_bf16_f32 %0, %1, %2" : "=v"(t) : "v"(lo0), "v"(lo1));
  lp = t;
}

// ---------------- merged prep ----------------
// blocks 0..2047  : cx[b,n,h] = x@W1x + b1 ; cy[b,m,h] = y@W1y    (2 rows/block)
// blocks 2048..2111: W1d -> hi/lo bf16 fragments in MFMA B-layout
//   frag[kstep(4)][htile(8)][lane(64)][i(8)], k = ks*32+8*(lane>>4)+i, h = ht*16+(lane&15)
__global__ __launch_bounds__(256) void prep_all(
    const float* __restrict__ x, const float* __restrict__ y,
    const float* __restrict__ W1, const float* __restrict__ b1,
    float* __restrict__ cx, float* __restrict__ cy,
    unsigned short* __restrict__ bhi, unsigned short* __restrict__ blo)
{
  const int blk = blockIdx.x;
  if (blk < 2048) {
    const int row = blk * 2 + (threadIdx.x >> 7);   // 0..4095
    const int h = threadIdx.x & 127;
    const bool isX = row < B_ * N_;
    const int r = isX ? row : row - B_ * N_;
    const float* src = (isX ? x : y) + (size_t)r * D_;
    const float* W = W1 + (isX ? 0 : D_ * H_);
    float acc = isX ? b1[h] : 0.f;
#pragma unroll
    for (int d0 = 0; d0 < D_; d0 += 4) {
      const f32x4 s = *(const f32x4*)(src + d0);
      acc = fmaf(s.x, W[(d0 + 0) * H_ + h], acc);
      acc = fmaf(s.y, W[(d0 + 1) * H_ + h], acc);
      acc = fmaf(s.z, W[(d0 + 2) * H_ + h], acc);
      acc = fmaf(s.w, W[(d0 + 3) * H_ + h], acc);
    }
    (isX ? cx : cy)[(size_t)r * H_ + h] = acc;
  } else {
    const int t = (blk - 2048) * 256 + threadIdx.x;   // 0..16383
    const int i    = t & 7;
    const int lane = (t >> 3) & 63;
    const int ht   = (t >> 9) & 7;
    const int ks   = t >> 12;
    const int k = ks * 32 + ((lane >> 4) << 3) + i;
    const int h = ht * 16 + (lane & 15);
    const float v = W1[(size_t)(2 * D_ + k) * H_ + h];
    const unsigned short hi = f2bf(v);
    bhi[t] = hi;
    blo[t] = f2bf(v - bf2f(hi));
  }
}

// ---------------- main fused kernel ----------------
// grid: (mblock=4, npair=256, b=4), 512 threads = 8 waves.
// waves 0-3 -> n = 2*npair, waves 4-7 -> n = 2*npair+1 (shared LDS B-stage).
// each wave: 32 m (2 MFMA row-tiles) x 128 h (8 col-tiles).
__global__ __launch_bounds__(512, 4) void fused_main(
    const float* __restrict__ x, const float* __restrict__ y,
    const float* __restrict__ gamma, const float* __restrict__ beta,
    const float* __restrict__ W2, const float* __restrict__ b2,
    const float* __restrict__ cx, const float* __restrict__ cy,
    const unsigned short* __restrict__ bhi, float* __restrict__ out)
{
  __shared__ char smem[65536];           // [hi 32KB][lo 32KB] fragment order

  const int tid = threadIdx.x;
  const int mblock = blockIdx.x, b = blockIdx.z;

  {
    const f32x4* src = (const f32x4*)bhi;   // bhi||blo contiguous 64KB
    f32x4* dst = (f32x4*)smem;
#pragma unroll
    for (int i = 0; i < 8; ++i)
      dst[i * 512 + tid] = src[i * 512 + tid];
  }
  __syncthreads();

  const int wave = tid >> 6, lane = tid & 63, g = lane >> 4, c = lane & 15;
  const int n = blockIdx.y * 2 + (wave >> 2);
  const int m0 = mblock * 128 + (wave & 3) * 32;
  const float* xrow = x + (size_t)(b * N_ + n) * D_;

  f32x4 acc[2][8];
#pragma unroll
  for (int mt = 0; mt < 2; ++mt)
#pragma unroll
    for (int ht = 0; ht < 8; ++ht)
      acc[mt][ht] = (f32x4){0.f, 0.f, 0.f, 0.f};

#pragma unroll
  for (int ks = 0; ks < 4; ++ks) {
    const int d0 = ks * 32 + g * 8;
    f32x4 xa0 = *(const f32x4*)(xrow + d0);
    f32x4 xa1 = *(const f32x4*)(xrow + d0 + 4);

    short8 ahi[2], alo[2];
#pragma unroll
    for (int mt = 0; mt < 2; ++mt) {
      const int m = m0 + mt * 16 + c;     // A rows indexed by lane&15
      const float* yrow = y + (size_t)(b * M_ + m) * D_ + d0;
      f32x4 ya0 = *(const f32x4*)(yrow);
      f32x4 ya1 = *(const f32x4*)(yrow + 4);
      unsigned h0, h1, h2, h3, l0, l1, l2, l3;
      split2(xa0.x - ya0.x, xa0.y - ya0.y, h0, l0);
      split2(xa0.z - ya0.z, xa0.w - ya0.w, h1, l1);
      split2(xa1.x - ya1.x, xa1.y - ya1.y, h2, l2);
      split2(xa1.z - ya1.z, xa1.w - ya1.w, h3, l3);
      u32x4 hw = (u32x4){h0, h1, h2, h3};
      u32x4 lw = (u32x4){l0, l1, l2, l3};
      ahi[mt] = __builtin_bit_cast(short8, hw);
      alo[mt] = __builtin_bit_cast(short8, lw);
    }

    const char* base = smem + ((size_t)(ks * 8) * 64 + lane) * 16;
#pragma unroll
    for (int htp = 0; htp < 4; ++htp) {
      const int h0 = 2 * htp, h1 = 2 * htp + 1;
      const short8 bh0 = *(const short8*)(base + h0 * 1024);
      const short8 bh1 = *(const short8*)(base + h1 * 1024);
      const short8 bl0 = *(const short8*)(base + 32768 + h0 * 1024);
      const short8 bl1 = *(const short8*)(base + 32768 + h1 * 1024);
      // pass-major order: dependent reuses of each acc are 4 MFMAs apart
      acc[0][h0] = __builtin_amdgcn_mfma_f32_16x16x32_bf16(ahi[0], bh0, acc[0][h0], 0, 0, 0);
      acc[1][h0] = __builtin_amdgcn_mfma_f32_16x16x32_bf16(ahi[1], bh0, acc[1][h0], 0, 0, 0);
      acc[0][h1] = __builtin_amdgcn_mfma_f32_16x16x32_bf16(ahi[0], bh1, acc[0][h1], 0, 0, 0);
      acc[1][h1] = __builtin_amdgcn_mfma_f32_16x16x32_bf16(ahi[1], bh1, acc[1][h1], 0, 0, 0);
      acc[0][h0] = __builtin_amdgcn_mfma_f32_16x16x32_bf16(alo[0], bh0, acc[0][h0], 0, 0, 0);
      acc[1][h0] = __builtin_amdgcn_mfma_f32_16x16x32_bf16(alo[1], bh0, acc[1][h0], 0, 0, 0);
      acc[0][h1] = __builtin_amdgcn_mfma_f32_16x16x32_bf16(alo[0], bh1, acc[0][h1], 0, 0, 0);
      acc[1][h1] = __builtin_amdgcn_mfma_f32_16x16x32_bf16(alo[1], bh1, acc[1][h1], 0, 0, 0);
      acc[0][h0] = __builtin_amdgcn_mfma_f32_16x16x32_bf16(ahi[0], bl0, acc[0][h0], 0, 0, 0);
      acc[1][h0] = __builtin_amdgcn_mfma_f32_16x16x32_bf16(ahi[1], bl0, acc[1][h0], 0, 0, 0);
      acc[0][h1] = __builtin_amdgcn_mfma_f32_16x16x32_bf16(ahi[0], bl1, acc[0][h1], 0, 0, 0);
      acc[1][h1] = __builtin_amdgcn_mfma_f32_16x16x32_bf16(ahi[1], bl1, acc[1][h1], 0, 0, 0);
    }
  }

  // ---------------- epilogue: + cx + cy, LayerNorm(H), ReLU, dot W2, +b2, ReLU ----------------
  const float* cxn = cx + (size_t)(b * N_ + n) * H_;
  float cxv[8], gv[8], bev[8], w2v[8];
#pragma unroll
  for (int ht = 0; ht < 8; ++ht) {
    const int h = ht * 16 + c;
    cxv[ht] = cxn[h]; gv[ht] = gamma[h]; bev[ht] = beta[h]; w2v[ht] = W2[h];
  }
  const float b2v = b2[0];

#pragma unroll
  for (int mt = 0; mt < 2; ++mt) {
#pragma unroll
    for (int r = 0; r < 4; ++r) {
      const int m = m0 + mt * 16 + g * 4 + r;      // C/D rows: (lane>>4)*4 + reg
      const float* cyrow = cy + (size_t)(b * M_ + m) * H_;
      float hv[8];
      float s1 = 0.f, s2 = 0.f;
#pragma unroll
      for (int ht = 0; ht < 8; ++ht) {
        const float v = acc[mt][ht][r] + cxv[ht] + cyrow[ht * 16 + c];
        hv[ht] = v; s1 += v; s2 += v * v;
      }
#pragma unroll
      for (int msk = 1; msk < 16; msk <<= 1) {
        s1 += __shfl_xor(s1, msk);
        s2 += __shfl_xor(s2, msk);
      }
      const float mu = s1 * (1.f / 128.f);
      const float var = s2 * (1.f / 128.f) - mu * mu;
      const float rs = rsqrtf(var + EPS);
      float o = 0.f;
#pragma unroll
      for (int ht = 0; ht < 8; ++ht) {
        const float hn = (hv[ht] - mu) * rs * gv[ht] + bev[ht];
        o += fmaxf(hn, 0.f) * w2v[ht];
      }
#pragma unroll
      for (int msk = 1; msk < 16; msk <<= 1)
        o += __shfl_xor(o, msk);
      if (c == 0)
        out[(size_t)(b * N_ + n) * M_ + m] = fmaxf(o + b2v, 0.f);
    }
  }
}

extern "C" void kernel_launch(void* const* d_in, const int* in_sizes, int n_in,
                              void* d_out, int out_size, void* d_ws, size_t ws_size,
                              hipStream_t stream) {
  const float* x     = (const float*)d_in[0];
  const float* y     = (const float*)d_in[1];
  const float* W1    = (const float*)d_in[2];
  const float* b1    = (const float*)d_in[3];
  const float* gamma = (const float*)d_in[4];
  const float* beta  = (const float*)d_in[5];
  const float* W2    = (const float*)d_in[6];
  const float* b2    = (const float*)d_in[7];
  float* out = (float*)d_out;

  char* ws = (char*)d_ws;
  float* cx = (float*)ws;                                  // 1MB
  float* cy = (float*)(ws + (1 << 20));                    // 1MB
  unsigned short* bhi = (unsigned short*)(ws + (2 << 20)); // 32KB
  unsigned short* blo = bhi + 16384;                       // contiguous 32KB

  prep_all<<<dim3(2112), dim3(256), 0, stream>>>(x, y, W1, b1, cx, cy, bhi, blo);
  fused_main<<<dim3(M_ / 128, N_ / 2, B_), dim3(512), 0, stream>>>(
      x, y, gamma, beta, W2, b2, cx, cy, bhi, out);
}